// Round 1
// baseline (3288.206 us; speedup 1.0000x reference)
//
#include <hip/hip_runtime.h>
#include <cstdint>

// ---------------------------------------------------------------------------
// GCN Siamese network:
//   branch(x, ei, batch): h1 = relu(GCNConv(x,W1,b1)); h2 = relu(GCNConv(h1,W2,b2));
//                         emb = mean_pool(h2, batch)
//   out = sigmoid(relu([e1,e2,|e1-e2|] @ fc1 + b) @ fc2 + b2)
// N=100000 nodes, E=3.2M edges, G=1024 graphs, F_IN=128, H=64
// ---------------------------------------------------------------------------

__device__ __forceinline__ float fatomic(float* p, float v) {
    return unsafeAtomicAdd(p, v);   // hw global_atomic_add_f32 on gfx950
}

// degree: deg[dst[e]] += 1
__global__ void k_deg(const int* __restrict__ dst, float* __restrict__ deg, int E) {
    int i = blockIdx.x * blockDim.x + threadIdx.x;
    int stride = gridDim.x * blockDim.x;
    for (; i < E; i += stride) fatomic(&deg[dst[i]], 1.0f);
}

// dinv = rsqrt(deg + 1)
__global__ void k_rsqrt(float* __restrict__ d, int n) {
    int i = blockIdx.x * blockDim.x + threadIdx.x;
    if (i < n) d[i] = rsqrtf(d[i] + 1.0f);
}

// Y[n,64] = X[n,K] @ W[K,64].  256 thr/block, 32 rows/block.
// col = tid&63 (lane), rowgroup = tid>>6 (wave-uniform -> broadcast LDS reads).
template <int K>
__global__ __launch_bounds__(256) void k_mm(const float* __restrict__ X,
                                            const float* __restrict__ W,
                                            float* __restrict__ Y, int n) {
    __shared__ float WL[K * 64];
    __shared__ float XT[32 * K];
    const int tid = threadIdx.x;

    for (int i = tid * 4; i < K * 64; i += 256 * 4)
        *(float4*)&WL[i] = *(const float4*)&W[i];

    const int rowBase = blockIdx.x * 32;
    const float* xsrc = X + (size_t)rowBase * K;
    for (int i = tid * 4; i < 32 * K; i += 256 * 4)
        *(float4*)&XT[i] = *(const float4*)&xsrc[i];
    __syncthreads();

    const int col = tid & 63;
    const int rg  = tid >> 6;          // wave-uniform
    float acc[8] = {};
    for (int k4 = 0; k4 < K / 4; ++k4) {
        const float w0 = WL[(k4 * 4 + 0) * 64 + col];
        const float w1 = WL[(k4 * 4 + 1) * 64 + col];
        const float w2 = WL[(k4 * 4 + 2) * 64 + col];
        const float w3 = WL[(k4 * 4 + 3) * 64 + col];
#pragma unroll
        for (int r = 0; r < 8; ++r) {
            const float4 xv = *(const float4*)&XT[(rg * 8 + r) * K + k4 * 4];
            acc[r] += xv.x * w0 + xv.y * w1 + xv.z * w2 + xv.w * w3;
        }
    }
#pragma unroll
    for (int r = 0; r < 8; ++r)
        Y[(size_t)(rowBase + rg * 8 + r) * 64 + col] = acc[r];
}

// edge aggregation: AGG[dst] += dinv[src]*dinv[dst] * XW[src]
// one wave per edge, lane = feature (coalesced 256B gather + 256B atomic)
__global__ void k_edge(const int* __restrict__ src, const int* __restrict__ dst,
                       const float* __restrict__ dinv, const float* __restrict__ XW,
                       float* __restrict__ AGG, int E) {
    const int lane = threadIdx.x & 63;
    int wid = (blockIdx.x * blockDim.x + threadIdx.x) >> 6;
    const int nw = (gridDim.x * blockDim.x) >> 6;
    for (int e = wid; e < E; e += nw) {
        const int s = src[e], d = dst[e];
        const float nrm = dinv[s] * dinv[d];
        const float v = nrm * XW[(size_t)s * 64 + lane];
        fatomic(&AGG[(size_t)d * 64 + lane], v);
    }
}

// h = relu(agg + dinv^2 * xw + bias)   (in-place on AGG)
__global__ void k_fin(float* __restrict__ AGG, const float* __restrict__ XW,
                      const float* __restrict__ dinv, const float* __restrict__ bias,
                      int total) {
    int i = blockIdx.x * blockDim.x + threadIdx.x;
    if (i >= total) return;
    const int nd = i >> 6, f = i & 63;
    const float di = dinv[nd];
    const float v = AGG[i] + di * di * XW[i] + bias[f];
    AGG[i] = fmaxf(v, 0.0f);
}

// mean-pool numerators + counts. batch is sorted: blocked ranges + register
// run-length accumulation -> few atomics per graph.
__global__ void k_pool(const float* __restrict__ Hn, const int* __restrict__ batch,
                       float* __restrict__ emb, float* __restrict__ cnt, int n) {
    const int lane = threadIdx.x & 63;
    const int wid = (blockIdx.x * blockDim.x + threadIdx.x) >> 6;
    const int nw = (gridDim.x * blockDim.x) >> 6;
    const int per = (n + nw - 1) / nw;
    const int s = wid * per;
    const int e = min(s + per, n);
    if (s >= e) return;
    float acc = 0.0f;
    int curg = -1, run = 0;
    for (int nd = s; nd < e; ++nd) {
        const int g = batch[nd];
        if (g != curg) {
            if (curg >= 0) {
                fatomic(&emb[(size_t)curg * 64 + lane], acc);
                if (lane == 0) fatomic(&cnt[curg], (float)run);
            }
            curg = g; acc = 0.0f; run = 0;
        }
        acc += Hn[(size_t)nd * 64 + lane];
        ++run;
    }
    fatomic(&emb[(size_t)curg * 64 + lane], acc);
    if (lane == 0) fatomic(&cnt[curg], (float)run);
}

// head: emb -> [e1,e2,|e1-e2|] @ fc1 -> relu -> @ fc2 -> sigmoid
__global__ __launch_bounds__(64) void k_head(const float* __restrict__ emb1, const float* __restrict__ cnt1,
                                             const float* __restrict__ emb2, const float* __restrict__ cnt2,
                                             const float* __restrict__ fc1W, const float* __restrict__ fc1b,
                                             const float* __restrict__ fc2W, const float* __restrict__ fc2b,
                                             float* __restrict__ out) {
    const int g = blockIdx.x;
    const int lane = threadIdx.x;
    __shared__ float comb[192];
    const float c1 = fmaxf(cnt1[g], 1.0f), c2 = fmaxf(cnt2[g], 1.0f);
    const float e1 = emb1[g * 64 + lane] / c1;
    const float e2 = emb2[g * 64 + lane] / c2;
    comb[lane] = e1;
    comb[64 + lane] = e2;
    comb[128 + lane] = fabsf(e1 - e2);
    __syncthreads();
    float acc = fc1b[lane];
    for (int k = 0; k < 192; ++k) acc += comb[k] * fc1W[k * 64 + lane];
    const float o1 = fmaxf(acc, 0.0f);
    float p = o1 * fc2W[lane];
#pragma unroll
    for (int off = 32; off > 0; off >>= 1) p += __shfl_xor(p, off);
    if (lane == 0) out[g] = 1.0f / (1.0f + expf(-(p + fc2b[0])));
}

extern "C" void kernel_launch(void* const* d_in, const int* in_sizes, int n_in,
                              void* d_out, int out_size, void* d_ws, size_t ws_size,
                              hipStream_t stream) {
    const float* x1   = (const float*)d_in[0];
    const int*   ei1  = (const int*)d_in[1];
    const int*   bt1  = (const int*)d_in[2];
    const float* x2   = (const float*)d_in[3];
    const int*   ei2  = (const int*)d_in[4];
    const int*   bt2  = (const int*)d_in[5];
    const float* W1   = (const float*)d_in[6];
    const float* bb1  = (const float*)d_in[7];
    const float* W2   = (const float*)d_in[8];
    const float* bb2  = (const float*)d_in[9];
    const float* fc1W = (const float*)d_in[10];
    const float* fc1b = (const float*)d_in[11];
    const float* fc2W = (const float*)d_in[12];
    const float* fc2b = (const float*)d_in[13];
    float* out = (float*)d_out;

    const int N = in_sizes[0] / 128;
    const int E = in_sizes[1] / 2;
    const int G = out_size;

    float* ws   = (float*)d_ws;
    float* A    = ws;                      // N*64  (xw / hw)
    float* B    = A + (size_t)N * 64;      // N*64  (agg / h)
    float* dinv = B + (size_t)N * 64;      // N
    float* emb1 = dinv + N;                // G*64
    float* cnt1 = emb1 + (size_t)G * 64;   // G
    float* emb2 = cnt1 + G;                // G*64
    float* cnt2 = emb2 + (size_t)G * 64;   // G

    for (int br = 0; br < 2; ++br) {
        const float* X = br ? x2 : x1;
        const int* ei  = br ? ei2 : ei1;
        const int* bt  = br ? bt2 : bt1;
        float* emb = br ? emb2 : emb1;
        float* cnt = br ? cnt2 : cnt1;
        const int* srcp = ei;
        const int* dstp = ei + E;

        hipMemsetAsync(dinv, 0, (size_t)N * 4, stream);
        hipMemsetAsync(emb, 0, (size_t)(G * 64 + G) * 4, stream);  // emb & cnt adjacent
        k_deg<<<2048, 256, 0, stream>>>(dstp, dinv, E);
        k_rsqrt<<<(N + 255) / 256, 256, 0, stream>>>(dinv, N);
        k_mm<128><<<N / 32, 256, 0, stream>>>(X, W1, A, N);
        hipMemsetAsync(B, 0, (size_t)N * 64 * 4, stream);
        k_edge<<<2048, 256, 0, stream>>>(srcp, dstp, dinv, A, B, E);
        k_fin<<<(N * 64 + 255) / 256, 256, 0, stream>>>(B, A, dinv, bb1, N * 64);
        k_mm<64><<<N / 32, 256, 0, stream>>>(B, W2, A, N);
        hipMemsetAsync(B, 0, (size_t)N * 64 * 4, stream);
        k_edge<<<2048, 256, 0, stream>>>(srcp, dstp, dinv, A, B, E);
        k_fin<<<(N * 64 + 255) / 256, 256, 0, stream>>>(B, A, dinv, bb2, N * 64);
        k_pool<<<2048, 256, 0, stream>>>(B, bt, emb, cnt, N);
    }
    k_head<<<G, 64, 0, stream>>>(emb1, cnt1, emb2, cnt2, fc1W, fc1b, fc2W, fc2b, out);
}

// Round 2
// 2086.634 us; speedup vs baseline: 1.5758x; 1.5758x over previous
//
#include <hip/hip_runtime.h>
#include <cstdint>

// ---------------------------------------------------------------------------
// GCN Siamese network, CSR-gather formulation.
//   per branch: hist(dst) -> scan -> scatter (counting sort by dst) ->
//     xw = X@W1 ; h1 = relu(gather-agg(xw) + selfloop + b1)       [k_agg<false>]
//     xw2 = h1@W2 ; pool-agg: emb[batch] += relu(agg2+selfloop+b2) [k_agg<true>]
//   head: sigmoid(relu([e1,e2,|e1-e2|]@fc1+b)@fc2+b)
// N=100000, E=3.2M, G=1024, F_IN=128, H=64
// ---------------------------------------------------------------------------

__device__ __forceinline__ float fatomic(float* p, float v) {
    return unsafeAtomicAdd(p, v);   // hw global_atomic_add_f32
}

// int histogram of dst -> degI
__global__ void k_hist(const int* __restrict__ dst, int* __restrict__ degI, int E) {
    int i = blockIdx.x * blockDim.x + threadIdx.x;
    int stride = gridDim.x * blockDim.x;
    for (; i < E; i += stride) atomicAdd(&degI[dst[i]], 1);
}

// single-block exclusive scan: cur[i] = prefix(degI), dinv[i] = rsqrt(deg+1)
__global__ __launch_bounds__(1024) void k_scan(const int* __restrict__ degI,
                                               int* __restrict__ cur,
                                               float* __restrict__ dinv, int n) {
    __shared__ int sm[1024];
    const int t = threadIdx.x;
    const int per = (n + 1023) / 1024;
    const int s = t * per, e = min(s + per, n);
    int sum = 0;
    for (int i = s; i < e; ++i) sum += degI[i];
    sm[t] = sum;
    __syncthreads();
    int inc = sum;
#pragma unroll
    for (int off = 1; off < 1024; off <<= 1) {
        int u = (t >= off) ? sm[t - off] : 0;
        __syncthreads();
        sm[t] += u;
        __syncthreads();
    }
    inc = sm[t] - sum;          // exclusive prefix for this chunk
    for (int i = s; i < e; ++i) {
        const int d = degI[i];
        cur[i] = inc;
        dinv[i] = rsqrtf((float)d + 1.0f);
        inc += d;
    }
}

// counting-sort scatter: col[pos++] = src   (after this, cur[i] == row end)
__global__ void k_scatter(const int* __restrict__ src, const int* __restrict__ dst,
                          int* __restrict__ cur, int* __restrict__ col, int E) {
    int i = blockIdx.x * blockDim.x + threadIdx.x;
    int stride = gridDim.x * blockDim.x;
    for (; i < E; i += stride) {
        const int pos = atomicAdd(&cur[dst[i]], 1);
        col[pos] = src[i];
    }
}

// Y[n,64] = X[n,K] @ W[K,64].  256 thr/block, 32 rows/block.
template <int K>
__global__ __launch_bounds__(256) void k_mm(const float* __restrict__ X,
                                            const float* __restrict__ W,
                                            float* __restrict__ Y, int n) {
    __shared__ float WL[K * 64];
    __shared__ float XT[32 * K];
    const int tid = threadIdx.x;

    for (int i = tid * 4; i < K * 64; i += 256 * 4)
        *(float4*)&WL[i] = *(const float4*)&W[i];

    const int rowBase = blockIdx.x * 32;
    const float* xsrc = X + (size_t)rowBase * K;
    for (int i = tid * 4; i < 32 * K; i += 256 * 4)
        *(float4*)&XT[i] = *(const float4*)&xsrc[i];
    __syncthreads();

    const int col = tid & 63;
    const int rg  = tid >> 6;          // wave-uniform
    float acc[8] = {};
    for (int k4 = 0; k4 < K / 4; ++k4) {
        const float w0 = WL[(k4 * 4 + 0) * 64 + col];
        const float w1 = WL[(k4 * 4 + 1) * 64 + col];
        const float w2 = WL[(k4 * 4 + 2) * 64 + col];
        const float w3 = WL[(k4 * 4 + 3) * 64 + col];
#pragma unroll
        for (int r = 0; r < 8; ++r) {
            const float4 xv = *(const float4*)&XT[(rg * 8 + r) * K + k4 * 4];
            acc[r] += xv.x * w0 + xv.y * w1 + xv.z * w2 + xv.w * w3;
        }
    }
#pragma unroll
    for (int r = 0; r < 8; ++r)
        Y[(size_t)(rowBase + rg * 8 + r) * 64 + col] = acc[r];
}

// CSR aggregation, one wave per dst node, lane = feature.
//   acc = sum_{s in row} dinv[s] * XW[s*64+lane]
//   v   = relu(dinv[i]*acc + dinv[i]^2*XW[i] + bias)
// POOL=false: H[i] = v.   POOL=true: emb[batch[i]] += v (atomic), cnt[g] += 1.
template <bool POOL>
__global__ void k_agg(const int* __restrict__ col, const int* __restrict__ cur,
                      const int* __restrict__ degI, const float* __restrict__ dinv,
                      const float* __restrict__ XW, const float* __restrict__ bias,
                      float* __restrict__ Hout, const int* __restrict__ batch,
                      float* __restrict__ emb, float* __restrict__ cnt, int n) {
    const int lane = threadIdx.x & 63;
    const int wid = (blockIdx.x * blockDim.x + threadIdx.x) >> 6;
    const int nw = (gridDim.x * blockDim.x) >> 6;
    const float bl = bias[lane];
    for (int i = wid; i < n; i += nw) {
        const int e1 = cur[i];
        const int e0 = e1 - degI[i];
        float acc = 0.0f;
        int j = e0;
        for (; j + 4 <= e1; j += 4) {
            const int s0 = col[j], s1 = col[j + 1], s2 = col[j + 2], s3 = col[j + 3];
            const float a0 = dinv[s0] * XW[(size_t)s0 * 64 + lane];
            const float a1 = dinv[s1] * XW[(size_t)s1 * 64 + lane];
            const float a2 = dinv[s2] * XW[(size_t)s2 * 64 + lane];
            const float a3 = dinv[s3] * XW[(size_t)s3 * 64 + lane];
            acc += (a0 + a1) + (a2 + a3);
        }
        for (; j < e1; ++j) {
            const int s = col[j];
            acc += dinv[s] * XW[(size_t)s * 64 + lane];
        }
        const float di = dinv[i];
        const float v = fmaxf(di * acc + di * di * XW[(size_t)i * 64 + lane] + bl, 0.0f);
        if (POOL) {
            const int g = batch[i];
            fatomic(&emb[(size_t)g * 64 + lane], v);
            if (lane == 0) fatomic(&cnt[g], 1.0f);
        } else {
            Hout[(size_t)i * 64 + lane] = v;
        }
    }
}

// head: emb -> [e1,e2,|e1-e2|] @ fc1 -> relu -> @ fc2 -> sigmoid
__global__ __launch_bounds__(64) void k_head(const float* __restrict__ emb1, const float* __restrict__ cnt1,
                                             const float* __restrict__ emb2, const float* __restrict__ cnt2,
                                             const float* __restrict__ fc1W, const float* __restrict__ fc1b,
                                             const float* __restrict__ fc2W, const float* __restrict__ fc2b,
                                             float* __restrict__ out) {
    const int g = blockIdx.x;
    const int lane = threadIdx.x;
    __shared__ float comb[192];
    const float c1 = fmaxf(cnt1[g], 1.0f), c2 = fmaxf(cnt2[g], 1.0f);
    const float e1 = emb1[g * 64 + lane] / c1;
    const float e2 = emb2[g * 64 + lane] / c2;
    comb[lane] = e1;
    comb[64 + lane] = e2;
    comb[128 + lane] = fabsf(e1 - e2);
    __syncthreads();
    float acc = fc1b[lane];
    for (int k = 0; k < 192; ++k) acc += comb[k] * fc1W[k * 64 + lane];
    const float o1 = fmaxf(acc, 0.0f);
    float p = o1 * fc2W[lane];
#pragma unroll
    for (int off = 32; off > 0; off >>= 1) p += __shfl_xor(p, off);
    if (lane == 0) out[g] = 1.0f / (1.0f + expf(-(p + fc2b[0])));
}

extern "C" void kernel_launch(void* const* d_in, const int* in_sizes, int n_in,
                              void* d_out, int out_size, void* d_ws, size_t ws_size,
                              hipStream_t stream) {
    const float* x1   = (const float*)d_in[0];
    const int*   ei1  = (const int*)d_in[1];
    const int*   bt1  = (const int*)d_in[2];
    const float* x2   = (const float*)d_in[3];
    const int*   ei2  = (const int*)d_in[4];
    const int*   bt2  = (const int*)d_in[5];
    const float* W1   = (const float*)d_in[6];
    const float* bb1  = (const float*)d_in[7];
    const float* W2   = (const float*)d_in[8];
    const float* bb2  = (const float*)d_in[9];
    const float* fc1W = (const float*)d_in[10];
    const float* fc1b = (const float*)d_in[11];
    const float* fc2W = (const float*)d_in[12];
    const float* fc2b = (const float*)d_in[13];
    float* out = (float*)d_out;

    const int N = in_sizes[0] / 128;
    const int E = in_sizes[1] / 2;
    const int G = out_size;

    char* wsb = (char*)d_ws;
    float* A    = (float*)wsb;                       // N*64 floats (xw)
    float* B    = A + (size_t)N * 64;                // N*64 floats (h1)
    float* dinv = B + (size_t)N * 64;                // N
    float* emb1 = dinv + N;                          // G*64
    float* cnt1 = emb1 + (size_t)G * 64;             // G
    float* emb2 = cnt1 + G;                          // G*64
    float* cnt2 = emb2 + (size_t)G * 64;             // G
    int*   degI = (int*)(cnt2 + G);                  // N
    int*   cur  = degI + N;                          // N
    int*   col  = cur + N;                           // E

    for (int br = 0; br < 2; ++br) {
        const float* X = br ? x2 : x1;
        const int* ei  = br ? ei2 : ei1;
        const int* bt  = br ? bt2 : bt1;
        float* emb = br ? emb2 : emb1;
        float* cnt = br ? cnt2 : cnt1;
        const int* srcp = ei;
        const int* dstp = ei + E;

        hipMemsetAsync(degI, 0, (size_t)N * 4, stream);
        k_hist<<<2048, 256, 0, stream>>>(dstp, degI, E);
        k_scan<<<1, 1024, 0, stream>>>(degI, cur, dinv, N);
        k_scatter<<<2048, 256, 0, stream>>>(srcp, dstp, cur, col, E);

        k_mm<128><<<N / 32, 256, 0, stream>>>(X, W1, A, N);
        k_agg<false><<<2048, 256, 0, stream>>>(col, cur, degI, dinv, A, bb1,
                                               B, nullptr, nullptr, nullptr, N);
        k_mm<64><<<N / 32, 256, 0, stream>>>(B, W2, A, N);
        hipMemsetAsync(emb, 0, (size_t)(G * 64 + G) * 4, stream);  // emb & cnt adjacent
        k_agg<true><<<2048, 256, 0, stream>>>(col, cur, degI, dinv, A, bb2,
                                              nullptr, bt, emb, cnt, N);
    }
    k_head<<<G, 64, 0, stream>>>(emb1, cnt1, emb2, cnt2, fc1W, fc1b, fc2W, fc2b, out);
}